// Round 1
// baseline (1343.866 us; speedup 1.0000x reference)
//
#include <hip/hip_runtime.h>

// Problem constants (match reference).
constexpr int SRC_SIZE  = 200000;
constexpr int DST_SIZE  = 50000;
constexpr int NUM_EDGES = 800000;
constexpr int FEAT      = 32;
constexpr int BATCH     = 4;

// Pass 1: norm[d] = sum_{e: dst_e = d} weights[e]
__global__ void norm_kernel(const int* __restrict__ dst,
                            const float* __restrict__ wts,
                            float* __restrict__ norm) {
    int e = blockIdx.x * blockDim.x + threadIdx.x;
    if (e < NUM_EDGES) {
        atomicAdd(&norm[dst[e]], wts[e]);
    }
}

// Pass 2: out[b, d, f] += (w_e / (norm[d]+1e-8)) * x[b, s, f]
// Thread = (edge, 4-feature group). 8 groups of 4 feats cover FEAT=32.
__global__ void scatter_kernel(const float* __restrict__ x,
                               const int* __restrict__ src,
                               const int* __restrict__ dst,
                               const float* __restrict__ wts,
                               const float* __restrict__ norm,
                               float* __restrict__ out) {
    long long tid = (long long)blockIdx.x * blockDim.x + threadIdx.x;
    if (tid >= (long long)NUM_EDGES * 8) return;
    int e = (int)(tid >> 3);
    int g = ((int)tid & 7) * 4;   // feature offset 0,4,...,28

    int s = src[e];
    int d = dst[e];
    float w = wts[e] / (norm[d] + 1e-8f);

#pragma unroll
    for (int b = 0; b < BATCH; ++b) {
        const float4 xv = *reinterpret_cast<const float4*>(
            x + ((size_t)b * SRC_SIZE + s) * FEAT + g);
        float* o = out + ((size_t)b * DST_SIZE + d) * FEAT + g;
        atomicAdd(o + 0, w * xv.x);
        atomicAdd(o + 1, w * xv.y);
        atomicAdd(o + 2, w * xv.z);
        atomicAdd(o + 3, w * xv.w);
    }
}

extern "C" void kernel_launch(void* const* d_in, const int* in_sizes, int n_in,
                              void* d_out, int out_size, void* d_ws, size_t ws_size,
                              hipStream_t stream) {
    const float* x   = (const float*)d_in[0];
    const int*   ei  = (const int*)d_in[1];    // (2, E) row-major: src then dst
    const float* wts = (const float*)d_in[2];

    const int* src = ei;
    const int* dst = ei + NUM_EDGES;

    float* out  = (float*)d_out;
    float* norm = (float*)d_ws;                // DST_SIZE floats of scratch

    // Zero-init accumulators every call (harness poisons, does not re-zero).
    hipMemsetAsync(norm, 0, (size_t)DST_SIZE * sizeof(float), stream);
    hipMemsetAsync(out, 0, (size_t)out_size * sizeof(float), stream);

    {
        int threads = 256;
        int blocks = (NUM_EDGES + threads - 1) / threads;
        norm_kernel<<<blocks, threads, 0, stream>>>(dst, wts, norm);
    }
    {
        long long total = (long long)NUM_EDGES * 8;
        int threads = 256;
        long long blocks = (total + threads - 1) / threads;
        scatter_kernel<<<(int)blocks, threads, 0, stream>>>(x, src, dst, wts, norm, out);
    }
}

// Round 2
// 293.897 us; speedup vs baseline: 4.5726x; 4.5726x over previous
//
#include <hip/hip_runtime.h>

constexpr int SRC_SIZE  = 200000;
constexpr int DST_SIZE  = 50000;
constexpr int NUM_EDGES = 800000;
constexpr int FEAT      = 32;
constexpr int BATCH     = 4;

// ---------- CSR build ----------

__global__ void count_norm_kernel(const int* __restrict__ dst,
                                  const float* __restrict__ wts,
                                  int* __restrict__ counts,
                                  float* __restrict__ norm) {
    int e = blockIdx.x * blockDim.x + threadIdx.x;
    if (e < NUM_EDGES) {
        int d = dst[e];
        atomicAdd(&counts[d], 1);
        atomicAdd(&norm[d], wts[e]);
    }
}

// Single-block exclusive scan of counts[DST_SIZE] -> offsets[DST_SIZE+1].
__global__ void scan_kernel(const int* __restrict__ counts,
                            int* __restrict__ offsets) {
    __shared__ int tmp[1024];
    __shared__ int carry;
    if (threadIdx.x == 0) carry = 0;
    __syncthreads();
    for (int base = 0; base < DST_SIZE; base += 1024) {
        int i = base + threadIdx.x;
        int v = (i < DST_SIZE) ? counts[i] : 0;
        tmp[threadIdx.x] = v;
        __syncthreads();
        for (int off = 1; off < 1024; off <<= 1) {
            int t = (threadIdx.x >= off) ? tmp[threadIdx.x - off] : 0;
            __syncthreads();
            tmp[threadIdx.x] += t;
            __syncthreads();
        }
        if (i < DST_SIZE) offsets[i] = carry + tmp[threadIdx.x] - v;  // exclusive
        int total = tmp[1023];
        __syncthreads();
        if (threadIdx.x == 0) carry += total;
        __syncthreads();
    }
    if (threadIdx.x == 0) offsets[DST_SIZE] = carry;  // == NUM_EDGES
}

__global__ void bin_kernel(const int* __restrict__ src,
                           const int* __restrict__ dst,
                           const float* __restrict__ wts,
                           const float* __restrict__ norm,
                           const int* __restrict__ offsets,
                           int* __restrict__ cursor,
                           int* __restrict__ bsrc,
                           float* __restrict__ bw) {
    int e = blockIdx.x * blockDim.x + threadIdx.x;
    if (e < NUM_EDGES) {
        int d = dst[e];
        int pos = atomicAdd(&cursor[d], 1);
        int idx = offsets[d] + pos;
        bsrc[idx] = src[e];
        bw[idx]   = wts[e] / (norm[d] + 1e-8f);
    }
}

// ---------- Gather (no atomics) ----------
// 8 lanes per dst row; each lane owns a float4 feature slice x 4 batches.
__global__ void gather_kernel(const float* __restrict__ x,
                              const int* __restrict__ offsets,
                              const int* __restrict__ bsrc,
                              const float* __restrict__ bw,
                              float* __restrict__ out) {
    int t = blockIdx.x * blockDim.x + threadIdx.x;
    int row = t >> 3;
    if (row >= DST_SIZE) return;
    int f4 = (t & 7) * 4;

    int start = offsets[row];
    int end   = offsets[row + 1];

    float4 acc[BATCH];
#pragma unroll
    for (int b = 0; b < BATCH; ++b) acc[b] = make_float4(0.f, 0.f, 0.f, 0.f);

    for (int e = start; e < end; ++e) {
        int s   = bsrc[e];
        float w = bw[e];
#pragma unroll
        for (int b = 0; b < BATCH; ++b) {
            const float4 xv = *reinterpret_cast<const float4*>(
                x + ((size_t)b * SRC_SIZE + s) * FEAT + f4);
            acc[b].x += w * xv.x;
            acc[b].y += w * xv.y;
            acc[b].z += w * xv.z;
            acc[b].w += w * xv.w;
        }
    }
#pragma unroll
    for (int b = 0; b < BATCH; ++b) {
        *reinterpret_cast<float4*>(
            out + ((size_t)b * DST_SIZE + row) * FEAT + f4) = acc[b];
    }
}

// ---------- Fallback (round-1 atomic path, used only if ws too small) ----------

__global__ void norm_kernel_fb(const int* __restrict__ dst,
                               const float* __restrict__ wts,
                               float* __restrict__ norm) {
    int e = blockIdx.x * blockDim.x + threadIdx.x;
    if (e < NUM_EDGES) atomicAdd(&norm[dst[e]], wts[e]);
}

__global__ void scatter_kernel_fb(const float* __restrict__ x,
                                  const int* __restrict__ src,
                                  const int* __restrict__ dst,
                                  const float* __restrict__ wts,
                                  const float* __restrict__ norm,
                                  float* __restrict__ out) {
    long long tid = (long long)blockIdx.x * blockDim.x + threadIdx.x;
    if (tid >= (long long)NUM_EDGES * 8) return;
    int e = (int)(tid >> 3);
    int g = ((int)tid & 7) * 4;
    int s = src[e];
    int d = dst[e];
    float w = wts[e] / (norm[d] + 1e-8f);
#pragma unroll
    for (int b = 0; b < BATCH; ++b) {
        const float4 xv = *reinterpret_cast<const float4*>(
            x + ((size_t)b * SRC_SIZE + s) * FEAT + g);
        float* o = out + ((size_t)b * DST_SIZE + d) * FEAT + g;
        atomicAdd(o + 0, w * xv.x);
        atomicAdd(o + 1, w * xv.y);
        atomicAdd(o + 2, w * xv.z);
        atomicAdd(o + 3, w * xv.w);
    }
}

extern "C" void kernel_launch(void* const* d_in, const int* in_sizes, int n_in,
                              void* d_out, int out_size, void* d_ws, size_t ws_size,
                              hipStream_t stream) {
    const float* x   = (const float*)d_in[0];
    const int*   ei  = (const int*)d_in[1];   // (2, E): src row then dst row
    const float* wts = (const float*)d_in[2];
    const int* src = ei;
    const int* dst = ei + NUM_EDGES;
    float* out = (float*)d_out;

    // Workspace layout (all 4-byte types).
    char* ws = (char*)d_ws;
    float* norm    = (float*)(ws);
    int*   counts  = (int*)(ws + 1 * (size_t)DST_SIZE * 4);
    int*   offsets = (int*)(ws + 2 * (size_t)DST_SIZE * 4);            // DST_SIZE+1
    int*   cursor  = (int*)(ws + (3 * (size_t)DST_SIZE + 1) * 4);
    int*   bsrc    = (int*)(ws + (4 * (size_t)DST_SIZE + 1) * 4);
    float* bw      = (float*)(ws + (4 * (size_t)DST_SIZE + 1 + (size_t)NUM_EDGES) * 4);
    size_t needed  = (4 * (size_t)DST_SIZE + 1 + 2 * (size_t)NUM_EDGES) * 4;

    if (ws_size < needed) {
        // Fallback: atomic scatter (correct, slower).
        hipMemsetAsync(norm, 0, (size_t)DST_SIZE * sizeof(float), stream);
        hipMemsetAsync(out, 0, (size_t)out_size * sizeof(float), stream);
        int threads = 256;
        norm_kernel_fb<<<(NUM_EDGES + threads - 1) / threads, threads, 0, stream>>>(dst, wts, norm);
        long long total = (long long)NUM_EDGES * 8;
        scatter_kernel_fb<<<(int)((total + threads - 1) / threads), threads, 0, stream>>>(
            x, src, dst, wts, norm, out);
        return;
    }

    hipMemsetAsync(norm,   0, (size_t)DST_SIZE * sizeof(float), stream);
    hipMemsetAsync(counts, 0, (size_t)DST_SIZE * sizeof(int), stream);
    hipMemsetAsync(cursor, 0, (size_t)DST_SIZE * sizeof(int), stream);

    int threads = 256;
    int eblocks = (NUM_EDGES + threads - 1) / threads;

    count_norm_kernel<<<eblocks, threads, 0, stream>>>(dst, wts, counts, norm);
    scan_kernel<<<1, 1024, 0, stream>>>(counts, offsets);
    bin_kernel<<<eblocks, threads, 0, stream>>>(src, dst, wts, norm, offsets, cursor, bsrc, bw);

    long long gthreads = (long long)DST_SIZE * 8;
    gather_kernel<<<(int)((gthreads + threads - 1) / threads), threads, 0, stream>>>(
        x, offsets, bsrc, bw, out);
}

// Round 3
// 239.520 us; speedup vs baseline: 5.6107x; 1.2270x over previous
//
#include <hip/hip_runtime.h>

constexpr int SRC_SIZE  = 200000;
constexpr int DST_SIZE  = 50000;
constexpr int NUM_EDGES = 800000;
constexpr int FEAT      = 32;
constexpr int BATCH     = 4;

// ---------- Pass 1: per-dst edge counts ----------
__global__ void count_kernel(const int* __restrict__ dst,
                             int* __restrict__ counts) {
    int e = blockIdx.x * blockDim.x + threadIdx.x;
    if (e < NUM_EDGES) atomicAdd(&counts[dst[e]], 1);
}

// ---------- Pass 2: exclusive scan, single block, thread-serial chunks ----------
__global__ void scan_kernel(const int* __restrict__ counts,
                            int* __restrict__ offsets) {
    __shared__ int sums[1024];
    constexpr int CHUNK = (DST_SIZE + 1023) / 1024;  // 49
    const int t = threadIdx.x;
    const int base = t * CHUNK;

    int local = 0;
    for (int i = 0; i < CHUNK; ++i) {
        int idx = base + i;
        if (idx < DST_SIZE) local += counts[idx];
    }
    sums[t] = local;
    __syncthreads();
    // Hillis-Steele inclusive scan over 1024 thread totals (10 steps).
    for (int off = 1; off < 1024; off <<= 1) {
        int v = (t >= off) ? sums[t - off] : 0;
        __syncthreads();
        sums[t] += v;
        __syncthreads();
    }
    int prefix = (t == 0) ? 0 : sums[t - 1];  // exclusive prefix for this chunk
    for (int i = 0; i < CHUNK; ++i) {
        int idx = base + i;
        if (idx < DST_SIZE) {
            offsets[idx] = prefix;
            prefix += counts[idx];
        }
    }
    if (t == 1023) offsets[DST_SIZE] = prefix;  // == NUM_EDGES
}

// ---------- Pass 3: bucket-scatter edges into CSR order ----------
// Reuses counts as the cursor via atomicSub (counts dead after scan).
__global__ void bin_kernel(const int* __restrict__ src,
                           const int* __restrict__ dst,
                           const float* __restrict__ wts,
                           const int* __restrict__ offsets,
                           int* __restrict__ counts,
                           int* __restrict__ bsrc,
                           float* __restrict__ bw) {
    int e = blockIdx.x * blockDim.x + threadIdx.x;
    if (e < NUM_EDGES) {
        int d = dst[e];
        int pos = atomicSub(&counts[d], 1) - 1;   // [0, count)
        int idx = offsets[d] + pos;
        bsrc[idx] = src[e];
        bw[idx]   = wts[e];                        // raw weight; normalize in gather
    }
}

// ---------- Pass 4: gather ----------
// Wave = 1 dst row. 64 lanes = 2 edges/iter x 32 (batch, float4-slice) slots.
// Accumulate raw-weighted sums + wsum; scale by 1/(wsum+eps) at the end.
__global__ void gather_kernel(const float* __restrict__ x,
                              const int* __restrict__ offsets,
                              const int* __restrict__ bsrc,
                              const float* __restrict__ bw,
                              float* __restrict__ out) {
    const int wave_in_block = threadIdx.x >> 6;
    const int row = blockIdx.x * (blockDim.x >> 6) + wave_in_block;
    if (row >= DST_SIZE) return;
    const int lane = threadIdx.x & 63;
    const int half = lane >> 5;         // which edge of the pair
    const int sub  = lane & 31;         // (batch, f4) slot
    const int b    = sub >> 3;
    const int f4   = (sub & 7) * 4;

    const int start = offsets[row];
    const int n     = offsets[row + 1] - start;

    float4 acc = make_float4(0.f, 0.f, 0.f, 0.f);
    float wsum = 0.f;

    for (int i = half; i < n; i += 2) {
        const int e = start + i;
        const int s = bsrc[e];
        const float w = bw[e];
        const float4 xv = *reinterpret_cast<const float4*>(
            x + ((size_t)b * SRC_SIZE + s) * FEAT + f4);
        acc.x += w * xv.x;
        acc.y += w * xv.y;
        acc.z += w * xv.z;
        acc.w += w * xv.w;
        wsum  += w;
    }

    // Combine the two halves (lane ^ 32).
    acc.x += __shfl_xor(acc.x, 32);
    acc.y += __shfl_xor(acc.y, 32);
    acc.z += __shfl_xor(acc.z, 32);
    acc.w += __shfl_xor(acc.w, 32);
    wsum  += __shfl_xor(wsum, 32);

    const float scale = 1.f / (wsum + 1e-8f);
    if (half == 0) {
        float4 o;
        o.x = acc.x * scale; o.y = acc.y * scale;
        o.z = acc.z * scale; o.w = acc.w * scale;
        *reinterpret_cast<float4*>(
            out + ((size_t)b * DST_SIZE + row) * FEAT + f4) = o;
    }
}

// ---------- Fallback (atomic path, used only if ws too small) ----------
__global__ void norm_kernel_fb(const int* __restrict__ dst,
                               const float* __restrict__ wts,
                               float* __restrict__ norm) {
    int e = blockIdx.x * blockDim.x + threadIdx.x;
    if (e < NUM_EDGES) atomicAdd(&norm[dst[e]], wts[e]);
}

__global__ void scatter_kernel_fb(const float* __restrict__ x,
                                  const int* __restrict__ src,
                                  const int* __restrict__ dst,
                                  const float* __restrict__ wts,
                                  const float* __restrict__ norm,
                                  float* __restrict__ out) {
    long long tid = (long long)blockIdx.x * blockDim.x + threadIdx.x;
    if (tid >= (long long)NUM_EDGES * 8) return;
    int e = (int)(tid >> 3);
    int g = ((int)tid & 7) * 4;
    int s = src[e];
    int d = dst[e];
    float w = wts[e] / (norm[d] + 1e-8f);
#pragma unroll
    for (int b = 0; b < BATCH; ++b) {
        const float4 xv = *reinterpret_cast<const float4*>(
            x + ((size_t)b * SRC_SIZE + s) * FEAT + g);
        float* o = out + ((size_t)b * DST_SIZE + d) * FEAT + g;
        atomicAdd(o + 0, w * xv.x);
        atomicAdd(o + 1, w * xv.y);
        atomicAdd(o + 2, w * xv.z);
        atomicAdd(o + 3, w * xv.w);
    }
}

extern "C" void kernel_launch(void* const* d_in, const int* in_sizes, int n_in,
                              void* d_out, int out_size, void* d_ws, size_t ws_size,
                              hipStream_t stream) {
    const float* x   = (const float*)d_in[0];
    const int*   ei  = (const int*)d_in[1];   // (2, E): src row then dst row
    const float* wts = (const float*)d_in[2];
    const int* src = ei;
    const int* dst = ei + NUM_EDGES;
    float* out = (float*)d_out;

    // Workspace layout (all 4-byte types).
    char* ws = (char*)d_ws;
    int*   counts  = (int*)(ws);
    int*   offsets = (int*)(ws + (size_t)DST_SIZE * 4);                 // DST_SIZE+1
    int*   bsrc    = (int*)(ws + (2 * (size_t)DST_SIZE + 1) * 4);
    float* bw      = (float*)(ws + (2 * (size_t)DST_SIZE + 1 + (size_t)NUM_EDGES) * 4);
    size_t needed  = (2 * (size_t)DST_SIZE + 1 + 2 * (size_t)NUM_EDGES) * 4;

    int threads = 256;
    int eblocks = (NUM_EDGES + threads - 1) / threads;

    if (ws_size < needed) {
        float* norm = (float*)d_ws;
        hipMemsetAsync(norm, 0, (size_t)DST_SIZE * sizeof(float), stream);
        hipMemsetAsync(out, 0, (size_t)out_size * sizeof(float), stream);
        norm_kernel_fb<<<eblocks, threads, 0, stream>>>(dst, wts, norm);
        long long total = (long long)NUM_EDGES * 8;
        scatter_kernel_fb<<<(int)((total + threads - 1) / threads), threads, 0, stream>>>(
            x, src, dst, wts, norm, out);
        return;
    }

    hipMemsetAsync(counts, 0, (size_t)DST_SIZE * sizeof(int), stream);

    count_kernel<<<eblocks, threads, 0, stream>>>(dst, counts);
    scan_kernel<<<1, 1024, 0, stream>>>(counts, offsets);
    bin_kernel<<<eblocks, threads, 0, stream>>>(src, dst, wts, offsets, counts, bsrc, bw);

    // 4 waves (4 rows) per block.
    int gblocks = (DST_SIZE + 3) / 4;
    gather_kernel<<<gblocks, 256, 0, stream>>>(x, offsets, bsrc, bw, out);
}

// Round 4
// 159.991 us; speedup vs baseline: 8.3996x; 1.4971x over previous
//
#include <hip/hip_runtime.h>

constexpr int SRC_SIZE  = 200000;
constexpr int DST_SIZE  = 50000;
constexpr int NUM_EDGES = 800000;
constexpr int FEAT      = 32;
constexpr int BATCH     = 4;

constexpr int SCAN_BLK  = 256;
constexpr int NBLK      = (DST_SIZE + SCAN_BLK - 1) / SCAN_BLK;  // 196

// ---------- Pass 1: per-dst edge counts ----------
__global__ void count_kernel(const int* __restrict__ dst,
                             int* __restrict__ counts) {
    int e = blockIdx.x * blockDim.x + threadIdx.x;
    if (e < NUM_EDGES) atomicAdd(&counts[dst[e]], 1);
}

// ---------- Pass 2a: per-block sums of counts ----------
__global__ void scan_partials_kernel(const int* __restrict__ counts,
                                     int* __restrict__ partials) {
    __shared__ int tmp[SCAN_BLK];
    int i = blockIdx.x * SCAN_BLK + threadIdx.x;
    tmp[threadIdx.x] = (i < DST_SIZE) ? counts[i] : 0;
    __syncthreads();
    for (int off = SCAN_BLK / 2; off > 0; off >>= 1) {
        if (threadIdx.x < off) tmp[threadIdx.x] += tmp[threadIdx.x + off];
        __syncthreads();
    }
    if (threadIdx.x == 0) partials[blockIdx.x] = tmp[0];
}

// ---------- Pass 2b: scan the 196 partials (one tiny block) ----------
__global__ void scan_root_kernel(int* __restrict__ partials,
                                 int* __restrict__ offsets) {
    __shared__ int tmp[SCAN_BLK];
    int t = threadIdx.x;
    int v = (t < NBLK) ? partials[t] : 0;
    tmp[t] = v;
    __syncthreads();
    for (int off = 1; off < SCAN_BLK; off <<= 1) {
        int u = (t >= off) ? tmp[t - off] : 0;
        __syncthreads();
        tmp[t] += u;
        __syncthreads();
    }
    if (t < NBLK) partials[t] = tmp[t] - v;           // exclusive block prefix
    if (t == NBLK - 1) offsets[DST_SIZE] = tmp[t];    // total == NUM_EDGES
}

// ---------- Pass 2c: block-local scan + block prefix -> offsets ----------
__global__ void scan_final_kernel(const int* __restrict__ counts,
                                  const int* __restrict__ partials,
                                  int* __restrict__ offsets) {
    __shared__ int tmp[SCAN_BLK];
    int i = blockIdx.x * SCAN_BLK + threadIdx.x;
    int v = (i < DST_SIZE) ? counts[i] : 0;
    tmp[threadIdx.x] = v;
    __syncthreads();
    for (int off = 1; off < SCAN_BLK; off <<= 1) {
        int u = (threadIdx.x >= off) ? tmp[threadIdx.x - off] : 0;
        __syncthreads();
        tmp[threadIdx.x] += u;
        __syncthreads();
    }
    if (i < DST_SIZE) offsets[i] = partials[blockIdx.x] + tmp[threadIdx.x] - v;
}

// ---------- Pass 3: bucket-scatter edges into CSR order ----------
// Reuses counts as the cursor via atomicSub (counts dead after scan).
__global__ void bin_kernel(const int* __restrict__ src,
                           const int* __restrict__ dst,
                           const float* __restrict__ wts,
                           const int* __restrict__ offsets,
                           int* __restrict__ counts,
                           int2* __restrict__ epack) {
    int e = blockIdx.x * blockDim.x + threadIdx.x;
    if (e < NUM_EDGES) {
        int d = dst[e];
        int pos = atomicSub(&counts[d], 1) - 1;   // [0, count)
        int idx = offsets[d] + pos;
        epack[idx] = make_int2(src[e], __float_as_int(wts[e]));
    }
}

// ---------- Pass 4: gather ----------
// Wave = 1 dst row. 64 lanes = 2 edges/iter x 32 (batch, float4-slice) slots.
__global__ void gather_kernel(const float* __restrict__ x,
                              const int* __restrict__ offsets,
                              const int2* __restrict__ epack,
                              float* __restrict__ out) {
    const int wave_in_block = threadIdx.x >> 6;
    const int row = blockIdx.x * (blockDim.x >> 6) + wave_in_block;
    if (row >= DST_SIZE) return;
    const int lane = threadIdx.x & 63;
    const int half = lane >> 5;         // which edge of the pair
    const int sub  = lane & 31;         // (batch, f4) slot
    const int b    = sub >> 3;
    const int f4   = (sub & 7) * 4;

    const int start = offsets[row];
    const int n     = offsets[row + 1] - start;

    float4 acc = make_float4(0.f, 0.f, 0.f, 0.f);
    float wsum = 0.f;

    for (int i = half; i < n; i += 2) {
        const int2 p = epack[start + i];
        const int s = p.x;
        const float w = __int_as_float(p.y);
        const float4 xv = *reinterpret_cast<const float4*>(
            x + ((size_t)b * SRC_SIZE + s) * FEAT + f4);
        acc.x += w * xv.x;
        acc.y += w * xv.y;
        acc.z += w * xv.z;
        acc.w += w * xv.w;
        wsum  += w;
    }

    acc.x += __shfl_xor(acc.x, 32);
    acc.y += __shfl_xor(acc.y, 32);
    acc.z += __shfl_xor(acc.z, 32);
    acc.w += __shfl_xor(acc.w, 32);
    wsum  += __shfl_xor(wsum, 32);

    const float scale = 1.f / (wsum + 1e-8f);
    if (half == 0) {
        float4 o;
        o.x = acc.x * scale; o.y = acc.y * scale;
        o.z = acc.z * scale; o.w = acc.w * scale;
        *reinterpret_cast<float4*>(
            out + ((size_t)b * DST_SIZE + row) * FEAT + f4) = o;
    }
}

// ---------- Fallback (atomic path, used only if ws too small) ----------
__global__ void norm_kernel_fb(const int* __restrict__ dst,
                               const float* __restrict__ wts,
                               float* __restrict__ norm) {
    int e = blockIdx.x * blockDim.x + threadIdx.x;
    if (e < NUM_EDGES) atomicAdd(&norm[dst[e]], wts[e]);
}

__global__ void scatter_kernel_fb(const float* __restrict__ x,
                                  const int* __restrict__ src,
                                  const int* __restrict__ dst,
                                  const float* __restrict__ wts,
                                  const float* __restrict__ norm,
                                  float* __restrict__ out) {
    long long tid = (long long)blockIdx.x * blockDim.x + threadIdx.x;
    if (tid >= (long long)NUM_EDGES * 8) return;
    int e = (int)(tid >> 3);
    int g = ((int)tid & 7) * 4;
    int s = src[e];
    int d = dst[e];
    float w = wts[e] / (norm[d] + 1e-8f);
#pragma unroll
    for (int b = 0; b < BATCH; ++b) {
        const float4 xv = *reinterpret_cast<const float4*>(
            x + ((size_t)b * SRC_SIZE + s) * FEAT + g);
        float* o = out + ((size_t)b * DST_SIZE + d) * FEAT + g;
        atomicAdd(o + 0, w * xv.x);
        atomicAdd(o + 1, w * xv.y);
        atomicAdd(o + 2, w * xv.z);
        atomicAdd(o + 3, w * xv.w);
    }
}

extern "C" void kernel_launch(void* const* d_in, const int* in_sizes, int n_in,
                              void* d_out, int out_size, void* d_ws, size_t ws_size,
                              hipStream_t stream) {
    const float* x   = (const float*)d_in[0];
    const int*   ei  = (const int*)d_in[1];   // (2, E): src row then dst row
    const float* wts = (const float*)d_in[2];
    const int* src = ei;
    const int* dst = ei + NUM_EDGES;
    float* out = (float*)d_out;

    // Workspace layout. epack first (8-byte aligned), then 4-byte arrays.
    char* ws = (char*)d_ws;
    int2*  epack   = (int2*)(ws);                                        // NUM_EDGES
    int*   counts  = (int*)(ws + (size_t)NUM_EDGES * 8);                 // DST_SIZE
    int*   offsets = (int*)(ws + (size_t)NUM_EDGES * 8 + (size_t)DST_SIZE * 4);  // DST_SIZE+1
    int*   partials= (int*)(ws + (size_t)NUM_EDGES * 8 + (2 * (size_t)DST_SIZE + 1) * 4); // NBLK
    size_t needed  = (size_t)NUM_EDGES * 8 + (2 * (size_t)DST_SIZE + 1 + NBLK) * 4;

    int threads = 256;
    int eblocks = (NUM_EDGES + threads - 1) / threads;

    if (ws_size < needed) {
        float* norm = (float*)d_ws;
        hipMemsetAsync(norm, 0, (size_t)DST_SIZE * sizeof(float), stream);
        hipMemsetAsync(out, 0, (size_t)out_size * sizeof(float), stream);
        norm_kernel_fb<<<eblocks, threads, 0, stream>>>(dst, wts, norm);
        long long total = (long long)NUM_EDGES * 8;
        scatter_kernel_fb<<<(int)((total + threads - 1) / threads), threads, 0, stream>>>(
            x, src, dst, wts, norm, out);
        return;
    }

    hipMemsetAsync(counts, 0, (size_t)DST_SIZE * sizeof(int), stream);

    count_kernel<<<eblocks, threads, 0, stream>>>(dst, counts);
    scan_partials_kernel<<<NBLK, SCAN_BLK, 0, stream>>>(counts, partials);
    scan_root_kernel<<<1, SCAN_BLK, 0, stream>>>(partials, offsets);
    scan_final_kernel<<<NBLK, SCAN_BLK, 0, stream>>>(counts, partials, offsets);
    bin_kernel<<<eblocks, threads, 0, stream>>>(src, dst, wts, offsets, counts, epack);

    // 4 waves (4 rows) per block.
    int gblocks = (DST_SIZE + 3) / 4;
    gather_kernel<<<gblocks, 256, 0, stream>>>(x, offsets, epack, out);
}